// Round 1
// baseline (168.772 us; speedup 1.0000x reference)
//
#include <hip/hip_runtime.h>

// DAREController route(is_visual=True, training=True)
// B=256 rows, S=32768 tokens. One block per row, exact per-row k-th-largest
// selection via 4-pass radix select on sign-flipped float keys held in regs.
//
// Outputs (flat, f32): keep_mask [B*S] (0/1), loss_ratio, loss_soft, loss_hard.
// Assumption: modality_mask (bool in reference) arrives as int32 per harness
// "integer -> const int*" rule.

#define NB 256
#define NS 32768
#define KAPPA 64
#define NT 1024
#define EPT (NS / NT)   // 32 elements per thread

__device__ __forceinline__ unsigned int fkey(float f) {
    unsigned int u = __float_as_uint(f);
    // monotone map: larger float -> larger unsigned key
    return (u & 0x80000000u) ? ~u : (u | 0x80000000u);
}

__device__ __forceinline__ float unkey(unsigned int k) {
    unsigned int u = (k & 0x80000000u) ? (k ^ 0x80000000u) : ~k;
    return __uint_as_float(u);
}

// Wave-aggregated histogram increment: dedup identical bins within the wave
// so LDS atomics are one-per-distinct-bin, not one-per-lane.
__device__ __forceinline__ void wave_hist_add(unsigned int* hist, int bin, bool active) {
    unsigned long long todo = __ballot(active);
    const int lane = threadIdx.x & 63;
    while (todo) {
        const int leader = __ffsll((unsigned long long)todo) - 1;
        const int b = __shfl(bin, leader);
        const unsigned long long same = __ballot(active && (bin == b));
        if (lane == leader) atomicAdd(&hist[b], (unsigned int)__popcll(same));
        todo &= ~same;
    }
}

__global__ __launch_bounds__(NT) void dare_rows(const float* __restrict__ imp,
                                                const int* __restrict__ mask,
                                                float* __restrict__ keep,
                                                float* __restrict__ stats) {
    __shared__ unsigned int hist[256];
    __shared__ unsigned int sh_mm, sh_eff;
    __shared__ unsigned int sh_pref;
    __shared__ int sh_rem;
    __shared__ int sh_kpos;
    __shared__ unsigned int sh_kept, sh_ndrop;
    __shared__ float sh_dsum;

    const int row = blockIdx.x;
    const int tid = threadIdx.x;
    const float* rimp = imp + (size_t)row * NS;
    const int*   rmask = mask + (size_t)row * NS;
    float*       rkeep = keep + (size_t)row * NS;

    if (tid < 256) hist[tid] = 0;
    if (tid == 0) { sh_mm = 0; sh_eff = 0; sh_kept = 0; sh_ndrop = 0; sh_dsum = 0.0f; }
    __syncthreads();

    // ---- Phase 1: single global scan -> registers; counts + top-byte hist ----
    unsigned int keys[EPT];
    unsigned int effbits = 0, mmbits = 0;

    #pragma unroll
    for (int i = 0; i < EPT; i++) {
        const int col = tid + i * NT;
        const int m = rmask[col];
        const float f = rimp[col];
        keys[i] = fkey(f);
        const bool mm  = (m != 0);
        const bool eff = mm && (col >= KAPPA);
        mmbits  |= (mm  ? 1u : 0u) << i;
        effbits |= (eff ? 1u : 0u) << i;
        wave_hist_add(hist, (int)(keys[i] >> 24), eff);
    }

    int mm_local  = __popc(mmbits);
    int eff_local = __popc(effbits);
    #pragma unroll
    for (int off = 32; off; off >>= 1) {
        mm_local  += __shfl_down(mm_local, off);
        eff_local += __shfl_down(eff_local, off);
    }
    if ((tid & 63) == 0) {
        atomicAdd(&sh_mm,  (unsigned int)mm_local);
        atomicAdd(&sh_eff, (unsigned int)eff_local);
    }
    __syncthreads();

    // ---- Select bin at radix level 0 (top byte) ----
    if (tid == 0) {
        const float target = fmaxf((float)sh_mm * 0.5f, 1.0f);  // clip(mm*rho, min=1)
        const int k = min((int)target, (int)sh_eff);             // trunc matches astype(int32)
        sh_kpos = (k > 0) ? 1 : 0;
        int rem = k;
        int b = 255;
        for (; b > 0; b--) {
            const int c = (int)hist[b];
            if (c >= rem) break;
            rem -= c;
        }
        sh_pref = ((unsigned int)b) << 24;
        sh_rem = rem;
    }
    __syncthreads();

    // ---- Radix passes 1..3 (bytes 2,1,0), operating on registers only ----
    for (int pass = 1; pass < 4; pass++) {
        if (tid < 256) hist[tid] = 0;
        __syncthreads();
        const int shift = 24 - 8 * pass;
        const unsigned int pmask = 0xFFFFFFFFu << (shift + 8);
        const unsigned int pref = sh_pref;
        #pragma unroll
        for (int i = 0; i < EPT; i++) {
            const bool eff = (effbits >> i) & 1u;
            const bool match = eff && ((keys[i] & pmask) == pref);
            wave_hist_add(hist, (int)((keys[i] >> shift) & 0xFFu), match);
        }
        __syncthreads();
        if (tid == 0) {
            int rem = sh_rem;
            int b = 255;
            for (; b > 0; b--) {
                const int c = (int)hist[b];
                if (c >= rem) break;
                rem -= c;
            }
            sh_pref = pref | (((unsigned int)b) << shift);
            sh_rem = rem;
        }
        __syncthreads();
    }

    // ---- Final: write keep mask, accumulate row stats ----
    const unsigned int thresh = sh_pref;   // exact key of k-th largest valid value
    const bool kpos = (sh_kpos != 0);

    int kept_l = 0, ndrop_l = 0;
    float dsum_l = 0.0f;
    #pragma unroll
    for (int i = 0; i < EPT; i++) {
        const int col = tid + i * NT;
        const bool mm  = (mmbits >> i) & 1u;
        const bool eff = (effbits >> i) & 1u;
        const bool hard = eff && kpos && (keys[i] >= thresh);
        const bool kp = (col < KAPPA) || hard;
        rkeep[col] = kp ? 1.0f : 0.0f;
        kept_l += (kp && mm) ? 1 : 0;
        const bool drop = mm && !kp;
        ndrop_l += drop ? 1 : 0;
        dsum_l += drop ? unkey(keys[i]) : 0.0f;
    }
    #pragma unroll
    for (int off = 32; off; off >>= 1) {
        kept_l  += __shfl_down(kept_l, off);
        ndrop_l += __shfl_down(ndrop_l, off);
        dsum_l  += __shfl_down(dsum_l, off);
    }
    if ((tid & 63) == 0) {
        atomicAdd(&sh_kept,  (unsigned int)kept_l);
        atomicAdd(&sh_ndrop, (unsigned int)ndrop_l);
        atomicAdd(&sh_dsum,  dsum_l);
    }
    __syncthreads();
    if (tid == 0) {
        stats[row * 4 + 0] = (float)sh_kept;
        stats[row * 4 + 1] = (float)sh_mm;
        stats[row * 4 + 2] = (float)sh_ndrop;
        stats[row * 4 + 3] = sh_dsum;
    }
}

__global__ __launch_bounds__(256) void dare_losses(const float* __restrict__ stats,
                                                   float* __restrict__ out) {
    __shared__ float w_a[4], w_h[4], w_n[4], w_d[4];
    const int tid = threadIdx.x;   // one thread per row
    const float kept = stats[tid * 4 + 0];
    const float mmc  = stats[tid * 4 + 1];
    const float nd   = stats[tid * 4 + 2];
    const float ds   = stats[tid * 4 + 3];
    const float ratio = kept / (mmc + 1e-6f);
    float a = fabsf(ratio - 0.5f);          // |ratio - rho|
    float h = fmaxf(0.5f - ratio, 0.0f);    // relu(rho - ratio)
    float n = nd, d = ds;
    #pragma unroll
    for (int off = 32; off; off >>= 1) {
        a += __shfl_down(a, off);
        h += __shfl_down(h, off);
        n += __shfl_down(n, off);
        d += __shfl_down(d, off);
    }
    const int wid = tid >> 6, lane = tid & 63;
    if (lane == 0) { w_a[wid] = a; w_h[wid] = h; w_n[wid] = n; w_d[wid] = d; }
    __syncthreads();
    if (tid == 0) {
        float sa = 0.f, shh = 0.f, sn = 0.f, sd = 0.f;
        for (int w = 0; w < 4; w++) { sa += w_a[w]; shh += w_h[w]; sn += w_n[w]; sd += w_d[w]; }
        out[0] = sa / (float)NB;                                        // 1.0 * loss_ratio
        out[1] = (sn > 0.0f) ? 0.1f * (sd / fmaxf(sn, 1.0f)) : 0.0f;    // 0.1 * loss_soft
        out[2] = shh / (float)NB;                                       // 1.0 * loss_hard
    }
}

extern "C" void kernel_launch(void* const* d_in, const int* in_sizes, int n_in,
                              void* d_out, int out_size, void* d_ws, size_t ws_size,
                              hipStream_t stream) {
    const float* imp  = (const float*)d_in[0];
    const int*   mask = (const int*)d_in[1];
    float* out   = (float*)d_out;
    float* stats = (float*)d_ws;   // 256 rows * 4 floats = 4 KB

    dare_rows<<<NB, NT, 0, stream>>>(imp, mask, out, stats);
    dare_losses<<<1, 256, 0, stream>>>(stats, out + (size_t)NB * NS);
}

// Round 2
// 111.411 us; speedup vs baseline: 1.5149x; 1.5149x over previous
//
#include <hip/hip_runtime.h>

// DAREController route(is_visual=True, training=True)
// B=256 rows, S=32768 tokens. One block per row; exact per-row k-th-largest
// via 4-pass 8-bit radix select on sign-flipped float keys held in registers.
//
// R1 -> R2 changes (latency-bound fix):
//  - plain LDS atomicAdd histogram (ds_add, no return) instead of the serial
//    ballot-dedup loop (whose per-iteration ds_bpermute latency dominated)
//  - parallel suffix-sum bin selection (256 threads) instead of tid==0's
//    serial 256-iteration dependent-LDS-read scan
//  - float4/int4 global loads, float4 stores

#define NB 256
#define NS 32768
#define KAPPA 64
#define NT 1024
#define V4 (NS / NT / 4)   // 8 float4 per thread

__device__ __forceinline__ unsigned int fkey(float f) {
    unsigned int u = __float_as_uint(f);
    return (u & 0x80000000u) ? ~u : (u | 0x80000000u);  // monotone: bigger float -> bigger key
}

__device__ __forceinline__ float unkey(unsigned int k) {
    unsigned int u = (k & 0x80000000u) ? (k ^ 0x80000000u) : ~k;
    return __uint_as_float(u);
}

__global__ __launch_bounds__(NT) void dare_rows(const float* __restrict__ imp,
                                                const int* __restrict__ mask,
                                                float* __restrict__ keep,
                                                float* __restrict__ stats) {
    __shared__ unsigned int hist[256];
    __shared__ unsigned int wtot[4];
    __shared__ unsigned int sh_mm, sh_eff;
    __shared__ unsigned int sh_pref;
    __shared__ unsigned int sh_rem;
    __shared__ unsigned int sh_kept, sh_ndrop;
    __shared__ float sh_dsum;

    const int row = blockIdx.x;
    const int tid = threadIdx.x;
    const int lane = tid & 63;
    const float4* rimp4  = (const float4*)(imp  + (size_t)row * NS);
    const int4*   rmask4 = (const int4*)  (mask + (size_t)row * NS);
    float4*       rkeep4 = (float4*)      (keep + (size_t)row * NS);

    if (tid < 256) hist[tid] = 0;
    if (tid == 0) {
        sh_mm = 0; sh_eff = 0; sh_kept = 0; sh_ndrop = 0; sh_dsum = 0.0f;
        sh_pref = 0; sh_rem = 1;
    }
    __syncthreads();

    // ---- Phase 1: one global scan -> registers; counts + pass-0 histogram ----
    unsigned int keys[V4 * 4];
    unsigned int effbits = 0, mmbits = 0;

    #pragma unroll
    for (int i = 0; i < V4; i++) {
        const int idx4 = tid + i * NT;          // float4 index; col = idx4*4 + j
        const float4 v = rimp4[idx4];
        const int4   m = rmask4[idx4];
        const float vv[4] = {v.x, v.y, v.z, v.w};
        const int    mv[4] = {m.x, m.y, m.z, m.w};
        #pragma unroll
        for (int j = 0; j < 4; j++) {
            const int e = i * 4 + j;
            const int col = idx4 * 4 + j;
            keys[e] = fkey(vv[j]);
            const bool mm  = (mv[j] != 0);
            const bool eff = mm && (col >= KAPPA);
            mmbits  |= (mm  ? 1u : 0u) << e;
            effbits |= (eff ? 1u : 0u) << e;
            if (eff) atomicAdd(&hist[keys[e] >> 24], 1u);  // fire-and-forget ds_add
        }
    }

    int mm_local  = __popc(mmbits);
    int eff_local = __popc(effbits);
    #pragma unroll
    for (int off = 32; off; off >>= 1) {
        mm_local  += __shfl_down(mm_local, off);
        eff_local += __shfl_down(eff_local, off);
    }
    if (lane == 0) {
        atomicAdd(&sh_mm,  (unsigned int)mm_local);
        atomicAdd(&sh_eff, (unsigned int)eff_local);
    }
    __syncthreads();

    // ---- Radix passes: parallel suffix-scan bin selection each pass ----
    #pragma unroll
    for (int pass = 0; pass < 4; pass++) {
        const int shift = 24 - 8 * pass;

        if (pass > 0) {
            // rebuild histogram for elements matching the selected prefix
            if (tid < 256) hist[tid] = 0;
            __syncthreads();
            const unsigned int pmask = 0xFFFFFFFFu << (shift + 8);
            const unsigned int pref = sh_pref;
            #pragma unroll
            for (int e = 0; e < V4 * 4; e++) {
                const bool match = ((effbits >> e) & 1u) && ((keys[e] & pmask) == pref);
                if (match) atomicAdd(&hist[(keys[e] >> shift) & 0xFFu], 1u);
            }
            __syncthreads();
        }

        // parallel select: largest bin b with suffix_sum(b) >= rem
        unsigned int h = 0, s = 0;
        if (tid < 256) {
            h = hist[tid];
            s = h;
            #pragma unroll
            for (int off = 1; off < 64; off <<= 1) {
                const unsigned int t = __shfl_down(s, off);
                if (lane + off < 64) s += t;
            }
            if (lane == 0) wtot[tid >> 6] = s;   // wave-suffix total
        }
        __syncthreads();
        if (tid < 256) {
            unsigned int sfull = s;
            for (int w = (tid >> 6) + 1; w < 4; w++) sfull += wtot[w];
            unsigned int rem;
            if (pass == 0) {
                const float target = fmaxf((float)sh_mm * 0.5f, 1.0f);
                const int k = min((int)target, (int)sh_eff);
                rem = (unsigned int)max(k, 1);
            } else {
                rem = sh_rem;
            }
            // unique crossing bin: suffix(t) >= rem > suffix(t+1) = sfull - h
            if (sfull >= rem && (sfull - h) < rem) {
                sh_pref = (pass == 0) ? ((unsigned int)tid << 24)
                                      : (sh_pref | ((unsigned int)tid << shift));
                sh_rem = rem - (sfull - h);
            }
        }
        __syncthreads();
    }

    // ---- Final: write keep mask (float4), accumulate row stats ----
    const unsigned int thresh = sh_pref;   // exact key of k-th largest valid value
    const float targetf = fmaxf((float)sh_mm * 0.5f, 1.0f);
    const bool kpos = (min((int)targetf, (int)sh_eff) > 0);

    int kept_l = 0, ndrop_l = 0;
    float dsum_l = 0.0f;
    #pragma unroll
    for (int i = 0; i < V4; i++) {
        const int idx4 = tid + i * NT;
        float ov[4];
        #pragma unroll
        for (int j = 0; j < 4; j++) {
            const int e = i * 4 + j;
            const int col = idx4 * 4 + j;
            const bool mm  = (mmbits >> e) & 1u;
            const bool eff = (effbits >> e) & 1u;
            const bool hard = eff && kpos && (keys[e] >= thresh);
            const bool kp = (col < KAPPA) || hard;
            ov[j] = kp ? 1.0f : 0.0f;
            kept_l += (kp && mm) ? 1 : 0;
            const bool drop = mm && !kp;
            ndrop_l += drop ? 1 : 0;
            dsum_l += drop ? unkey(keys[e]) : 0.0f;
        }
        float4 o; o.x = ov[0]; o.y = ov[1]; o.z = ov[2]; o.w = ov[3];
        rkeep4[idx4] = o;
    }
    #pragma unroll
    for (int off = 32; off; off >>= 1) {
        kept_l  += __shfl_down(kept_l, off);
        ndrop_l += __shfl_down(ndrop_l, off);
        dsum_l  += __shfl_down(dsum_l, off);
    }
    if (lane == 0) {
        atomicAdd(&sh_kept,  (unsigned int)kept_l);
        atomicAdd(&sh_ndrop, (unsigned int)ndrop_l);
        atomicAdd(&sh_dsum,  dsum_l);
    }
    __syncthreads();
    if (tid == 0) {
        stats[row * 4 + 0] = (float)sh_kept;
        stats[row * 4 + 1] = (float)sh_mm;
        stats[row * 4 + 2] = (float)sh_ndrop;
        stats[row * 4 + 3] = sh_dsum;
    }
}

__global__ __launch_bounds__(256) void dare_losses(const float* __restrict__ stats,
                                                   float* __restrict__ out) {
    __shared__ float w_a[4], w_h[4], w_n[4], w_d[4];
    const int tid = threadIdx.x;   // one thread per row
    const float kept = stats[tid * 4 + 0];
    const float mmc  = stats[tid * 4 + 1];
    const float nd   = stats[tid * 4 + 2];
    const float ds   = stats[tid * 4 + 3];
    const float ratio = kept / (mmc + 1e-6f);
    float a = fabsf(ratio - 0.5f);          // |ratio - rho|
    float h = fmaxf(0.5f - ratio, 0.0f);    // relu(rho - ratio)
    float n = nd, d = ds;
    #pragma unroll
    for (int off = 32; off; off >>= 1) {
        a += __shfl_down(a, off);
        h += __shfl_down(h, off);
        n += __shfl_down(n, off);
        d += __shfl_down(d, off);
    }
    const int wid = tid >> 6, lane = tid & 63;
    if (lane == 0) { w_a[wid] = a; w_h[wid] = h; w_n[wid] = n; w_d[wid] = d; }
    __syncthreads();
    if (tid == 0) {
        float sa = 0.f, shh = 0.f, sn = 0.f, sd = 0.f;
        for (int w = 0; w < 4; w++) { sa += w_a[w]; shh += w_h[w]; sn += w_n[w]; sd += w_d[w]; }
        out[0] = sa / (float)NB;                                        // 1.0 * loss_ratio
        out[1] = (sn > 0.0f) ? 0.1f * (sd / fmaxf(sn, 1.0f)) : 0.0f;    // 0.1 * loss_soft
        out[2] = shh / (float)NB;                                       // 1.0 * loss_hard
    }
}

extern "C" void kernel_launch(void* const* d_in, const int* in_sizes, int n_in,
                              void* d_out, int out_size, void* d_ws, size_t ws_size,
                              hipStream_t stream) {
    const float* imp  = (const float*)d_in[0];
    const int*   mask = (const int*)d_in[1];
    float* out   = (float*)d_out;
    float* stats = (float*)d_ws;   // 256 rows * 4 floats = 4 KB

    dare_rows<<<NB, NT, 0, stream>>>(imp, mask, out, stats);
    dare_losses<<<1, 256, 0, stream>>>(stats, out + (size_t)NB * NS);
}